// Round 1
// baseline (611.243 us; speedup 1.0000x reference)
//
#include <hip/hip_runtime.h>

// ISNE gather + masked-mean, wave-per-(row,side) layout.
// Inputs:
//   0: node_parameters [1e6, 128] f32
//   1: node_indices    [16384]    i32
//   2: pos_idx         [16384,32] i32
//   3: pos_len         [16384]    i32
//   4: neg_idx         [16384,32] i32
//   5: neg_len         [16384]    i32
// Output: concat(node_embeds, pos_embeds, neg_embeds), each [16384,128] f32.
//
// Layout: 256 threads = 4 waves. Wave w handles (b = 2*blk + (w>>1), side = w&1).
// Each lane owns float2 slice [2*lane, 2*lane+1] of the 128-float row ->
// accumulation is lane-local (no LDS / syncthreads / shuffles).
// len is wave-uniform (readfirstlane) -> whole 8-row chunks with base >= len
// are skipped by a uniform branch (avg 19.4 of 32 rows loaded vs 32 before).
// All 32 indices come from ONE coalesced 128B load, broadcast via v_readlane
// (constant lane after unroll) -> row addresses are scalar (saddr loads),
// no per-load vector 64-bit address chains.

constexpr int B = 16384;
constexpr int K = 32;

__global__ __launch_bounds__(256) void isne_kernel(
    const float* __restrict__ table,
    const int*   __restrict__ node_idx,
    const int*   __restrict__ pos_idx,
    const int*   __restrict__ pos_len,
    const int*   __restrict__ neg_idx,
    const int*   __restrict__ neg_len,
    float*       __restrict__ out)
{
    const int tid  = threadIdx.x;
    const int wave = tid >> 6;        // 0..3
    const int lane = tid & 63;
    const int b    = blockIdx.x * 2 + (wave >> 1);
    const int side = wave & 1;        // 0 = pos, 1 = neg

    const float2* t2   = reinterpret_cast<const float2*>(table);
    float2*       out2 = reinterpret_cast<float2*>(out);

    // Node embedding copy: waves 0 and 2 (side==0), one 512B load+store.
    if (side == 0) {
        const int ni = __builtin_amdgcn_readfirstlane(node_idx[b]);
        out2[(size_t)b * 64 + lane] = t2[(size_t)ni * 64 + lane];
    }

    const int* idxp = (side ? neg_idx : pos_idx) + b * K;
    const int  len  = __builtin_amdgcn_readfirstlane((side ? neg_len : pos_len)[b]);

    // One coalesced 128B load fetches all 32 list indices for this wave.
    const int myidx = idxp[lane & 31];
    const int sidx0 = __builtin_amdgcn_readlane(myidx, 0);

    float2 acc = make_float2(0.f, 0.f);

#pragma unroll
    for (int c = 0; c < 4; ++c) {
        const int base = c * 8;
        if (len > base) {            // wave-uniform: skips whole chunk
            float2 v[8];
#pragma unroll
            for (int j = 0; j < 8; ++j) {
                const int k = base + j;
                int sidx = __builtin_amdgcn_readlane(myidx, base + j); // scalar
                sidx = (k < len) ? sidx : sidx0;   // clamp -> L1 hit, no HBM
                v[j] = t2[(size_t)sidx * 64 + lane];   // 8 x 512B in flight
            }
#pragma unroll
            for (int j = 0; j < 8; ++j) {
                const float w = ((base + j) < len) ? 1.0f : 0.0f;
                acc.x += v[j].x * w;
                acc.y += v[j].y * w;
            }
        }
    }

    const float inv = (len > 0) ? (1.0f / (float)len) : 0.0f;
    acc.x *= inv;
    acc.y *= inv;

    // pos rows at [B, 2B), neg rows at [2B, 3B).
    out2[((size_t)(1 + side) * B + b) * 64 + lane] = acc;
}

extern "C" void kernel_launch(void* const* d_in, const int* in_sizes, int n_in,
                              void* d_out, int out_size, void* d_ws, size_t ws_size,
                              hipStream_t stream)
{
    const float* table    = (const float*)d_in[0];
    const int*   node_idx = (const int*)d_in[1];
    const int*   pos_idx  = (const int*)d_in[2];
    const int*   pos_len  = (const int*)d_in[3];
    const int*   neg_idx  = (const int*)d_in[4];
    const int*   neg_len  = (const int*)d_in[5];
    float*       out      = (float*)d_out;

    isne_kernel<<<B / 2, 256, 0, stream>>>(table, node_idx, pos_idx, pos_len,
                                           neg_idx, neg_len, out);
}